// Round 4
// baseline (258.686 us; speedup 1.0000x reference)
//
#include <hip/hip_runtime.h>
#include <math.h>

#define NCLS 80
#define A_TOT 8400
#define TOPK 10
#define BLK 256            // threads per block (4 waves)
#define NB_A 64            // assign blocks, first in grid order
#define NB_F 2048          // focal blocks; 2112 total ~= full-device wave capacity + slack
#define NB_TOT (NB_A + NB_F)
#define CAND_CAP 1536      // max anchors inside one gt box is ~1073
#define CHUNK 1024         // float4s per chunk = BLK * 4 (64 B per lane per iteration)

// ---------- helpers ----------

__device__ __forceinline__ void anchor_of(int a, float& cx, float& cy, float& st) {
    if (a < 6400)      { int r = a / 80;          int c = a - r * 80;          cx = (c + 0.5f) * 8.0f;  cy = (r + 0.5f) * 8.0f;  st = 8.0f;  }
    else if (a < 8000) { int i = a - 6400; int r = i / 40; int c = i - r * 40; cx = (c + 0.5f) * 16.0f; cy = (r + 0.5f) * 16.0f; st = 16.0f; }
    else               { int i = a - 8000; int r = i / 20; int c = i - r * 20; cx = (c + 0.5f) * 32.0f; cy = (r + 0.5f) * 32.0f; st = 32.0f; }
}

// fast reciprocal: v_rcp_f32 + 1 Newton step (~0.5 ulp), fma form (2 VALU)
__device__ __forceinline__ float rcp_nr(float x) {
    float r0 = __builtin_amdgcn_rcpf(x);
    return r0 * __builtin_fmaf(-x, r0, 2.0f);
}

// focal with target 0: 0.75 * softplus(l) * sigmoid(l)^2
// Direct form: w = e^l; softplus = ln(1+w); sigmoid = w/(1+w).
__device__ __forceinline__ float focal0(float l) {
    float w = __expf(l);
    float u = 1.0f + w;
    float r = rcp_nr(u);
    float p = w * r;                           // sigmoid(l)
    float s = __log2f(u) * 0.51986038542f;     // 0.75*ln(u)
    return s * (p * p);
}

// general focal term (alpha=0.25, gamma=2) — only for the ~640 kept anchors
__device__ __forceinline__ float focal_t(float l, float t) {
    float e  = __expf(-fabsf(l));
    float ce = fmaxf(l, 0.0f) - l * t + __logf(1.0f + e);
    float r  = rcp_nr(1.0f + e);
    float p  = (l >= 0.0f) ? r : e * r;
    float pt = p * t + (1.0f - p) * (1.0f - t);
    float at = 0.75f - 0.5f * t;
    float om = 1.0f - pt;
    return at * ce * om * om;
}

__device__ __forceinline__ float ciou_(float b1x1, float b1y1, float b1x2, float b1y2,
                                       float b2x1, float b2y1, float b2x2, float b2y2) {
    const float EPS = 1e-7f;
    float w1 = b1x2 - b1x1, h1 = b1y2 - b1y1;
    float w2 = b2x2 - b2x1, h2 = b2y2 - b2y1;
    float iw = fmaxf(fminf(b1x2, b2x2) - fmaxf(b1x1, b2x1), 0.0f);
    float ih = fmaxf(fminf(b1y2, b2y2) - fmaxf(b1y1, b2y1), 0.0f);
    float inter = iw * ih;
    float uni = w1 * h1 + w2 * h2 - inter + EPS;
    float iou = inter / uni;
    float cw = fmaxf(b1x2, b2x2) - fminf(b1x1, b2x1);
    float ch = fmaxf(b1y2, b2y2) - fminf(b1y1, b2y1);
    float c2 = cw * cw + ch * ch + EPS;
    float dx = b2x1 + b2x2 - b1x1 - b1x2;
    float dy = b2y1 + b2y2 - b1y1 - b1y2;
    float rho2 = (dx * dx + dy * dy) * 0.25f;
    const float k = 4.0f / (float)(M_PI * M_PI);
    float dv = atanf(w2 / (h2 + EPS)) - atanf(w1 / (h1 + EPS));
    float v = k * dv * dv;
    float alpha = v / (v - iou + 1.0f + EPS);
    return 1.0f - iou + rho2 / c2 + alpha * v;
}

__device__ __forceinline__ float focal4(const float4& v) {
    return (focal0(v.x) + focal0(v.y)) + (focal0(v.z) + focal0(v.w));
}

// ---------- fused kernel ----------
// Blocks [0,NB_A): per-image assignment (exit when done).
// Blocks [NB_A,NB_TOT): focal over 1024-float4 chunks, grid-stride by NB_F.
// 256-thread blocks at <=64 VGPR -> 8 blocks/CU co-resident (32 waves/CU).
// 2112 blocks oversubscribe ~2048 resident capacity: when an assign block
// retires, a queued focal block backfills its slot -> dynamic load balance
// with zero synchronization. 64 B/lane/iter (4 independent float4 loads).

__global__ __launch_bounds__(BLK, 8) void fused_kernel(const float* __restrict__ pred_boxes,
                                                       const float* __restrict__ pred_scores,
                                                       const float* __restrict__ gt_bboxes,
                                                       const int* __restrict__ gt_labels,
                                                       float* __restrict__ ws_focal,  // [NB_F]
                                                       float* __restrict__ ws_corr,   // [B]
                                                       float* __restrict__ ws_box,    // [B]
                                                       int*   __restrict__ ws_np,     // [B]
                                                       int n4) {
    const int tid = threadIdx.x;

    __shared__ float s_rv[4];
    __shared__ int   s_ri[4];

    if (blockIdx.x >= NB_A) {
        // ---- focal: chunked stream, 4 float4s per thread per chunk ----
        const int fb = blockIdx.x - NB_A;
        const float4* p4 = (const float4*)pred_scores;
        float a0 = 0.0f, a1 = 0.0f;
        for (int c = fb; c * CHUNK < n4; c += NB_F) {
            const int base = c * CHUNK + tid;
            const int i0 = base, i1 = base + BLK, i2 = base + 2 * BLK, i3 = base + 3 * BLK;
            const bool h0 = i0 < n4, h1 = i1 < n4, h2 = i2 < n4, h3 = i3 < n4;
            float4 v0, v1, v2, v3;
            if (h0) v0 = p4[i0];
            if (h1) v1 = p4[i1];
            if (h2) v2 = p4[i2];
            if (h3) v3 = p4[i3];
            if (h0) a0 += focal4(v0);
            if (h1) a1 += focal4(v1);
            if (h2) a0 += focal4(v2);
            if (h3) a1 += focal4(v3);
        }
        float acc = a0 + a1;
        for (int o = 32; o > 0; o >>= 1) acc += __shfl_down(acc, o, 64);
        if ((tid & 63) == 0) s_rv[tid >> 6] = acc;
        __syncthreads();
        if (tid < 64) {
            float v = (tid < 4) ? s_rv[tid] : 0.0f;
            for (int o = 2; o > 0; o >>= 1) v += __shfl_down(v, o, 64);
            if (tid == 0) ws_focal[fb] = v;
        }
        return;
    }

    // ---- assignment for image b ----
    const int b = blockIdx.x;

    __shared__ int   s_cnt;
    __shared__ float s_cm[CAND_CAP];
    __shared__ int   s_ci[CAND_CAP];
    __shared__ int   t_idx[TOPK];
    __shared__ float t_val[TOPK];
    __shared__ float s_corr[TOPK], s_boxl[TOPK];
    __shared__ int   s_keep[TOPK];

    const float gcx = gt_bboxes[b * 4 + 0], gcy = gt_bboxes[b * 4 + 1];
    const float gw  = gt_bboxes[b * 4 + 2], gh  = gt_bboxes[b * 4 + 3];
    const float gx1 = gcx - 0.5f * gw, gy1 = gcy - 0.5f * gh;
    const float gx2 = gcx + 0.5f * gw, gy2 = gcy + 0.5f * gh;
    const int   lb  = gt_labels[b];
    const bool  gt_valid = (gx2 > gx1) && (gy2 > gy1);
    const float garea = (gx2 - gx1) * (gy2 - gy1);
    const float gmx = 0.5f * (gx1 + gx2), gmy = 0.5f * (gy1 + gy2);

    if (tid == 0) s_cnt = 0;
    __syncthreads();

    float bestd = INFINITY;
    int   besti = 0x7fffffff;

    for (int a = tid; a < A_TOT; a += BLK) {
        float cx, cy, st;
        anchor_of(a, cx, cy, st);
        float4 pb = ((const float4*)pred_boxes)[b * A_TOT + a];
        float x1 = cx - fmaxf(pb.x, 0.0f) * st;
        float y1 = cy - fmaxf(pb.y, 0.0f) * st;
        float x2 = cx + fmaxf(pb.z, 0.0f) * st;
        float y2 = cy + fmaxf(pb.w, 0.0f) * st;
        bool inside = (cx >= gx1) && (cx <= gx2) && (cy >= gy1) && (cy <= gy2);
        if (inside) {
            float iw = fmaxf(fminf(x2, gx2) - fmaxf(x1, gx1), 0.0f);
            float ih = fmaxf(fminf(y2, gy2) - fmaxf(y1, gy1), 0.0f);
            float inter = iw * ih;
            float iou = fmaxf(inter / ((x2 - x1) * (y2 - y1) + garea - inter), 1e-9f);
            float sc = pred_scores[(size_t)(b * A_TOT + a) * NCLS + lb];
            float cls_s = 1.0f / (1.0f + __expf(-sc));
            float i2 = iou * iou;
            float m = sqrtf(cls_s) * i2 * i2 * i2;
            int pos = atomicAdd(&s_cnt, 1);
            if (pos < CAND_CAP) { s_cm[pos] = m; s_ci[pos] = a; }
        }
        float ddx = cx - gmx, ddy = cy - gmy;
        float d = ddx * ddx + ddy * ddy;
        if (d < bestd) { bestd = d; besti = a; }   // in-thread: increasing a, strict < keeps lowest idx
    }
    __syncthreads();
    int cnt = min(s_cnt, CAND_CAP);

    if (cnt == 0) {
        // fallback: nearest anchor (jnp.argmin semantics: lowest index on tie)
        float v = bestd; int i = besti;
        for (int o = 32; o > 0; o >>= 1) {
            float ov = __shfl_down(v, o, 64); int oi = __shfl_down(i, o, 64);
            if (ov < v || (ov == v && oi < i)) { v = ov; i = oi; }
        }
        if ((tid & 63) == 0) { s_rv[tid >> 6] = v; s_ri[tid >> 6] = i; }
        __syncthreads();
        if (tid < 64) {
            if (tid < 4) { v = s_rv[tid]; i = s_ri[tid]; }
            else         { v = INFINITY;  i = 0x7fffffff; }
            for (int o = 2; o > 0; o >>= 1) {
                float ov = __shfl_down(v, o, 64); int oi = __shfl_down(i, o, 64);
                if (ov < v || (ov == v && oi < i)) { v = ov; i = oi; }
            }
            if (tid == 0) {
                int a = i;
                float cx, cy, st;
                anchor_of(a, cx, cy, st);
                float4 pb = ((const float4*)pred_boxes)[b * A_TOT + a];
                float x1 = cx - fmaxf(pb.x, 0.0f) * st;
                float y1 = cy - fmaxf(pb.y, 0.0f) * st;
                float x2 = cx + fmaxf(pb.z, 0.0f) * st;
                float y2 = cy + fmaxf(pb.w, 0.0f) * st;
                float iw = fmaxf(fminf(x2, gx2) - fmaxf(x1, gx1), 0.0f);
                float ih = fmaxf(fminf(y2, gy2) - fmaxf(y1, gy1), 0.0f);
                float inter = iw * ih;
                float iou = fmaxf(inter / ((x2 - x1) * (y2 - y1) + garea - inter), 1e-9f);
                float sc = pred_scores[(size_t)(b * A_TOT + a) * NCLS + lb];
                float cls_s = 1.0f / (1.0f + __expf(-sc));
                float i2 = iou * iou;
                s_cm[0] = sqrtf(cls_s) * i2 * i2 * i2;
                s_ci[0] = a;
            }
        }
        __syncthreads();
        cnt = 1;
    }

    // ---- iterative top-10 over compacted candidates ----
    for (int k = 0; k < TOPK; k++) {
        float v = -INFINITY; int i = 0x7fffffff;
        for (int p = tid; p < cnt; p += BLK) {
            float m = s_cm[p]; int a = s_ci[p];
            if (m > v || (m == v && a < i)) { v = m; i = a; }
        }
        for (int o = 32; o > 0; o >>= 1) {
            float ov = __shfl_down(v, o, 64); int oi = __shfl_down(i, o, 64);
            if (ov > v || (ov == v && oi < i)) { v = ov; i = oi; }
        }
        if ((tid & 63) == 0) { s_rv[tid >> 6] = v; s_ri[tid >> 6] = i; }
        __syncthreads();
        if (tid < 64) {
            if (tid < 4) { v = s_rv[tid]; i = s_ri[tid]; }
            else         { v = -INFINITY; i = 0x7fffffff; }
            for (int o = 2; o > 0; o >>= 1) {
                float ov = __shfl_down(v, o, 64); int oi = __shfl_down(i, o, 64);
                if (ov > v || (ov == v && oi < i)) { v = ov; i = oi; }
            }
            if (tid == 0) { t_val[k] = v; t_idx[k] = i; }
        }
        __syncthreads();
        int wa = t_idx[k];
        if (t_val[k] > -INFINITY) {
            for (int p = tid; p < cnt; p += BLK)
                if (s_ci[p] == wa) s_cm[p] = -INFINITY;
        }
        __syncthreads();
    }

    // ---- per-kept-anchor: focal correction + ciou ----
    if (tid < TOPK) {
        int   a = t_idx[tid];
        float v = t_val[tid];
        int keep = (v > -INFINITY) && gt_valid;
        float corr = 0.0f, boxl = 0.0f;
        if (keep) {
            float cx, cy, st;
            anchor_of(a, cx, cy, st);
            float4 pb = ((const float4*)pred_boxes)[b * A_TOT + a];
            float x1 = cx - fmaxf(pb.x, 0.0f) * st;
            float y1 = cy - fmaxf(pb.y, 0.0f) * st;
            float x2 = cx + fmaxf(pb.z, 0.0f) * st;
            float y2 = cy + fmaxf(pb.w, 0.0f) * st;
            float iw = fmaxf(fminf(x2, gx2) - fmaxf(x1, gx1), 0.0f);
            float ih = fmaxf(fminf(y2, gy2) - fmaxf(y1, gy1), 0.0f);
            float inter = iw * ih;
            float t = fmaxf(inter / ((x2 - x1) * (y2 - y1) + garea - inter), 1e-9f);
            float l = pred_scores[(size_t)(b * A_TOT + a) * NCLS + lb];
            corr = focal_t(l, t) - focal0(l);
            boxl = ciou_(x1, y1, x2, y2, gx1, gy1, gx2, gy2);
        }
        s_corr[tid] = corr;
        s_boxl[tid] = boxl;
        s_keep[tid] = keep;
    }
    __syncthreads();
    if (tid == 0) {
        float cs = 0.0f, bs = 0.0f;
        int np = 0;
        for (int k = 0; k < TOPK; k++) { cs += s_corr[k]; bs += s_boxl[k]; np += s_keep[k]; }
        ws_corr[b] = cs;
        ws_box[b]  = bs;
        ws_np[b]   = np;
    }
}

// ---------- finalize: one wave reduces all partials ----------

__global__ __launch_bounds__(64) void finalize_kernel(const float* __restrict__ ws_focal,
                                                      const float* __restrict__ ws_corr,
                                                      const float* __restrict__ ws_box,
                                                      const int* __restrict__ ws_np,
                                                      float* __restrict__ out, int B) {
    int tid = threadIdx.x;
    float c = 0.0f, bx = 0.0f;
    int np = 0;
    for (int i = tid; i < NB_F; i += 64) c += ws_focal[i];
    for (int i = tid; i < B; i += 64) { c += ws_corr[i]; bx += ws_box[i]; np += ws_np[i]; }
    for (int o = 32; o > 0; o >>= 1) {
        c  += __shfl_down(c, o, 64);
        bx += __shfl_down(bx, o, 64);
        np += __shfl_down(np, o, 64);
    }
    if (tid == 0) {
        float npos = fmaxf((float)np, 1.0f);
        out[0] = c / npos + 2.5f * bx / npos;
    }
}

// ---------- launch ----------

extern "C" void kernel_launch(void* const* d_in, const int* in_sizes, int n_in,
                              void* d_out, int out_size, void* d_ws, size_t ws_size,
                              hipStream_t stream) {
    const float* pred_boxes  = (const float*)d_in[0];
    const float* pred_scores = (const float*)d_in[1];
    const float* gt_bboxes   = (const float*)d_in[2];
    const int*   gt_labels   = (const int*)d_in[3];
    float* out = (float*)d_out;

    const int B  = in_sizes[3];          // 64 images
    const int n4 = in_sizes[1] / 4;      // float4 count of pred_scores

    float* ws_focal = (float*)d_ws;          // [NB_F]
    float* ws_corr  = ws_focal + NB_F;       // [B]
    float* ws_box   = ws_corr + B;           // [B]
    int*   ws_np    = (int*)(ws_box + B);    // [B]

    fused_kernel<<<NB_TOT, BLK, 0, stream>>>(pred_boxes, pred_scores, gt_bboxes, gt_labels,
                                             ws_focal, ws_corr, ws_box, ws_np, n4);
    finalize_kernel<<<1, 64, 0, stream>>>(ws_focal, ws_corr, ws_box, ws_np, out, B);
}

// Round 5
// 238.643 us; speedup vs baseline: 1.0840x; 1.0840x over previous
//
#include <hip/hip_runtime.h>
#include <math.h>

#define NCLS 80
#define A_TOT 8400
#define TOPK 10
#define NB_A 64           // assign blocks (first, so they overlap focal)
#define NB_F 448          // focal-primary blocks; total grid = 512 = 2 blocks/CU
#define BLK 1024          // threads per block (fused kernel)
#define CAND_CAP 1536     // max anchors inside one gt box is ~1073
#define NB_TOT (NB_A + NB_F)
#define N_UNIT (2 * NB_F + NB_A)   // 960 strided units over pred_scores float4s

// ---------- helpers ----------

typedef float vfloat4 __attribute__((ext_vector_type(4)));

// non-temporal float4 load: no-allocate in L2/L3. The focal stream is
// one-touch, and the preceding 672MB workspace fill leaves L3 fully dirty —
// allocating reads force a dirty writeback per miss. NT avoids the storm.
__device__ __forceinline__ vfloat4 ldnt4(const vfloat4* p) {
    return __builtin_nontemporal_load(p);
}

__device__ __forceinline__ void anchor_of(int a, float& cx, float& cy, float& st) {
    if (a < 6400)      { int r = a / 80;          int c = a - r * 80;          cx = (c + 0.5f) * 8.0f;  cy = (r + 0.5f) * 8.0f;  st = 8.0f;  }
    else if (a < 8000) { int i = a - 6400; int r = i / 40; int c = i - r * 40; cx = (c + 0.5f) * 16.0f; cy = (r + 0.5f) * 16.0f; st = 16.0f; }
    else               { int i = a - 8000; int r = i / 20; int c = i - r * 20; cx = (c + 0.5f) * 32.0f; cy = (r + 0.5f) * 32.0f; st = 32.0f; }
}

// fast reciprocal: v_rcp_f32 + 1 Newton step (~0.5 ulp), fma form (2 VALU)
__device__ __forceinline__ float rcp_nr(float x) {
    float r0 = __builtin_amdgcn_rcpf(x);
    return r0 * __builtin_fmaf(-x, r0, 2.0f);
}

// focal with target 0: 0.75 * softplus(l) * sigmoid(l)^2
// Direct form: w = e^l; softplus = ln(1+w); sigmoid = w/(1+w).
__device__ __forceinline__ float focal0(float l) {
    float w = __expf(l);
    float u = 1.0f + w;
    float r = rcp_nr(u);
    float p = w * r;                           // sigmoid(l)
    float s = __log2f(u) * 0.51986038542f;     // 0.75*ln(u)
    return s * (p * p);
}

// general focal term (alpha=0.25, gamma=2) — only for the ~640 kept anchors
__device__ __forceinline__ float focal_t(float l, float t) {
    float e  = __expf(-fabsf(l));
    float ce = fmaxf(l, 0.0f) - l * t + __logf(1.0f + e);
    float r  = rcp_nr(1.0f + e);
    float p  = (l >= 0.0f) ? r : e * r;
    float pt = p * t + (1.0f - p) * (1.0f - t);
    float at = 0.75f - 0.5f * t;
    float om = 1.0f - pt;
    return at * ce * om * om;
}

__device__ __forceinline__ float ciou_(float b1x1, float b1y1, float b1x2, float b1y2,
                                       float b2x1, float b2y1, float b2x2, float b2y2) {
    const float EPS = 1e-7f;
    float w1 = b1x2 - b1x1, h1 = b1y2 - b1y1;
    float w2 = b2x2 - b2x1, h2 = b2y2 - b2y1;
    float iw = fmaxf(fminf(b1x2, b2x2) - fmaxf(b1x1, b2x1), 0.0f);
    float ih = fmaxf(fminf(b1y2, b2y2) - fmaxf(b1y1, b2y1), 0.0f);
    float inter = iw * ih;
    float uni = w1 * h1 + w2 * h2 - inter + EPS;
    float iou = inter / uni;
    float cw = fmaxf(b1x2, b2x2) - fminf(b1x1, b2x1);
    float ch = fmaxf(b1y2, b2y2) - fminf(b1y1, b2y1);
    float c2 = cw * cw + ch * ch + EPS;
    float dx = b2x1 + b2x2 - b1x1 - b1x2;
    float dy = b2y1 + b2y2 - b1y1 - b1y2;
    float rho2 = (dx * dx + dy * dy) * 0.25f;
    const float k = 4.0f / (float)(M_PI * M_PI);
    float dv = atanf(w2 / (h2 + EPS)) - atanf(w1 / (h1 + EPS));
    float v = k * dv * dv;
    float alpha = v / (v - iou + 1.0f + EPS);
    return 1.0f - iou + rho2 / c2 + alpha * v;
}

__device__ __forceinline__ float focal4v(const vfloat4& v) {
    return (focal0(v[0]) + focal0(v[1])) + (focal0(v[2]) + focal0(v[3]));
}

// ---------- fused kernel ----------
// Blocks [0,NB_A): assignment for image b, then one focal unit (half share).
// Blocks [NB_A,NB_TOT): two focal units (full share).
// pred_scores (as float4) is split into N_UNIT=960 strided combs: unit u
// covers { u*BLK + tid + k*N_UNIT*BLK }. Focal block fb owns units {2fb,2fb+1};
// assign block b owns unit 2*NB_F+b after its top-k finishes. Purely static.
// Focal stream loads are NON-TEMPORAL (see ldnt4).

__global__ __launch_bounds__(BLK) void fused_kernel(const float* __restrict__ pred_boxes,
                                                    const float* __restrict__ pred_scores,
                                                    const float* __restrict__ gt_bboxes,
                                                    const int* __restrict__ gt_labels,
                                                    float* __restrict__ ws_focal,  // [NB_TOT]
                                                    float* __restrict__ ws_corr,   // [B]
                                                    float* __restrict__ ws_box,    // [B]
                                                    int*   __restrict__ ws_np,     // [B]
                                                    int n4) {
    const int tid = threadIdx.x;

    __shared__ float s_rv[16];
    __shared__ int   s_ri[16];

    float acc = 0.0f;
    const vfloat4* p4 = (const vfloat4*)pred_scores;

    if (blockIdx.x >= NB_A) {
        // ---- focal: two strided units, non-temporal loads ----
        const int fb = blockIdx.x - NB_A;
        const int base = (2 * fb) * BLK + tid;
        for (int i = base; i < n4; i += N_UNIT * BLK) {
            vfloat4 v = ldnt4(p4 + i);
            acc += focal4v(v);
            int j = i + BLK;
            if (j < n4) {
                vfloat4 w = ldnt4(p4 + j);
                acc += focal4v(w);
            }
        }
        for (int o = 32; o > 0; o >>= 1) acc += __shfl_down(acc, o, 64);
        if ((tid & 63) == 0) s_rv[tid >> 6] = acc;
        __syncthreads();
        if (tid < 16) {
            float v = s_rv[tid];
            for (int o = 8; o > 0; o >>= 1) v += __shfl_down(v, o, 64);
            if (tid == 0) ws_focal[blockIdx.x] = v;
        }
        return;
    }

    // ---- assignment for image b ----
    const int b = blockIdx.x;

    __shared__ int   s_cnt;
    __shared__ float s_cm[CAND_CAP];
    __shared__ int   s_ci[CAND_CAP];
    __shared__ int   t_idx[TOPK];
    __shared__ float t_val[TOPK];
    __shared__ float s_corr[TOPK], s_boxl[TOPK];
    __shared__ int   s_keep[TOPK];

    const float gcx = gt_bboxes[b * 4 + 0], gcy = gt_bboxes[b * 4 + 1];
    const float gw  = gt_bboxes[b * 4 + 2], gh  = gt_bboxes[b * 4 + 3];
    const float gx1 = gcx - 0.5f * gw, gy1 = gcy - 0.5f * gh;
    const float gx2 = gcx + 0.5f * gw, gy2 = gcy + 0.5f * gh;
    const int   lb  = gt_labels[b];
    const bool  gt_valid = (gx2 > gx1) && (gy2 > gy1);
    const float garea = (gx2 - gx1) * (gy2 - gy1);
    const float gmx = 0.5f * (gx1 + gx2), gmy = 0.5f * (gy1 + gy2);

    if (tid == 0) s_cnt = 0;
    __syncthreads();

    float bestd = INFINITY;
    int   besti = 0x7fffffff;

    for (int a = tid; a < A_TOT; a += BLK) {
        float cx, cy, st;
        anchor_of(a, cx, cy, st);
        float4 pb = ((const float4*)pred_boxes)[b * A_TOT + a];
        float x1 = cx - fmaxf(pb.x, 0.0f) * st;
        float y1 = cy - fmaxf(pb.y, 0.0f) * st;
        float x2 = cx + fmaxf(pb.z, 0.0f) * st;
        float y2 = cy + fmaxf(pb.w, 0.0f) * st;
        bool inside = (cx >= gx1) && (cx <= gx2) && (cy >= gy1) && (cy <= gy2);
        if (inside) {
            float iw = fmaxf(fminf(x2, gx2) - fmaxf(x1, gx1), 0.0f);
            float ih = fmaxf(fminf(y2, gy2) - fmaxf(y1, gy1), 0.0f);
            float inter = iw * ih;
            float iou = fmaxf(inter / ((x2 - x1) * (y2 - y1) + garea - inter), 1e-9f);
            float sc = pred_scores[(size_t)(b * A_TOT + a) * NCLS + lb];
            float cls_s = 1.0f / (1.0f + __expf(-sc));
            float i2 = iou * iou;
            float m = sqrtf(cls_s) * i2 * i2 * i2;
            int pos = atomicAdd(&s_cnt, 1);
            if (pos < CAND_CAP) { s_cm[pos] = m; s_ci[pos] = a; }
        }
        float ddx = cx - gmx, ddy = cy - gmy;
        float d = ddx * ddx + ddy * ddy;
        if (d < bestd) { bestd = d; besti = a; }   // in-thread: increasing a, strict < keeps lowest idx
    }
    __syncthreads();
    int cnt = min(s_cnt, CAND_CAP);

    if (cnt == 0) {
        // fallback: nearest anchor (jnp.argmin semantics: lowest index on tie)
        float v = bestd; int i = besti;
        for (int o = 32; o > 0; o >>= 1) {
            float ov = __shfl_down(v, o, 64); int oi = __shfl_down(i, o, 64);
            if (ov < v || (ov == v && oi < i)) { v = ov; i = oi; }
        }
        if ((tid & 63) == 0) { s_rv[tid >> 6] = v; s_ri[tid >> 6] = i; }
        __syncthreads();
        if (tid < 16) {
            v = s_rv[tid]; i = s_ri[tid];
            for (int o = 8; o > 0; o >>= 1) {
                float ov = __shfl_down(v, o, 64); int oi = __shfl_down(i, o, 64);
                if (ov < v || (ov == v && oi < i)) { v = ov; i = oi; }
            }
            if (tid == 0) {
                int a = i;
                float cx, cy, st;
                anchor_of(a, cx, cy, st);
                float4 pb = ((const float4*)pred_boxes)[b * A_TOT + a];
                float x1 = cx - fmaxf(pb.x, 0.0f) * st;
                float y1 = cy - fmaxf(pb.y, 0.0f) * st;
                float x2 = cx + fmaxf(pb.z, 0.0f) * st;
                float y2 = cy + fmaxf(pb.w, 0.0f) * st;
                float iw = fmaxf(fminf(x2, gx2) - fmaxf(x1, gx1), 0.0f);
                float ih = fmaxf(fminf(y2, gy2) - fmaxf(y1, gy1), 0.0f);
                float inter = iw * ih;
                float iou = fmaxf(inter / ((x2 - x1) * (y2 - y1) + garea - inter), 1e-9f);
                float sc = pred_scores[(size_t)(b * A_TOT + a) * NCLS + lb];
                float cls_s = 1.0f / (1.0f + __expf(-sc));
                float i2 = iou * iou;
                s_cm[0] = sqrtf(cls_s) * i2 * i2 * i2;
                s_ci[0] = a;
            }
        }
        __syncthreads();
        cnt = 1;
    }

    // ---- iterative top-10 over compacted candidates ----
    for (int k = 0; k < TOPK; k++) {
        float v = -INFINITY; int i = 0x7fffffff;
        for (int p = tid; p < cnt; p += BLK) {
            float m = s_cm[p]; int a = s_ci[p];
            if (m > v || (m == v && a < i)) { v = m; i = a; }
        }
        for (int o = 32; o > 0; o >>= 1) {
            float ov = __shfl_down(v, o, 64); int oi = __shfl_down(i, o, 64);
            if (ov > v || (ov == v && oi < i)) { v = ov; i = oi; }
        }
        if ((tid & 63) == 0) { s_rv[tid >> 6] = v; s_ri[tid >> 6] = i; }
        __syncthreads();
        if (tid < 16) {
            v = s_rv[tid]; i = s_ri[tid];
            for (int o = 8; o > 0; o >>= 1) {
                float ov = __shfl_down(v, o, 64); int oi = __shfl_down(i, o, 64);
                if (ov > v || (ov == v && oi < i)) { v = ov; i = oi; }
            }
            if (tid == 0) { t_val[k] = v; t_idx[k] = i; }
        }
        __syncthreads();
        int wa = t_idx[k];
        if (t_val[k] > -INFINITY) {
            for (int p = tid; p < cnt; p += BLK)
                if (s_ci[p] == wa) s_cm[p] = -INFINITY;
        }
        __syncthreads();
    }

    // ---- per-kept-anchor: focal correction + ciou ----
    if (tid < TOPK) {
        int   a = t_idx[tid];
        float v = t_val[tid];
        int keep = (v > -INFINITY) && gt_valid;
        float corr = 0.0f, boxl = 0.0f;
        if (keep) {
            float cx, cy, st;
            anchor_of(a, cx, cy, st);
            float4 pb = ((const float4*)pred_boxes)[b * A_TOT + a];
            float x1 = cx - fmaxf(pb.x, 0.0f) * st;
            float y1 = cy - fmaxf(pb.y, 0.0f) * st;
            float x2 = cx + fmaxf(pb.z, 0.0f) * st;
            float y2 = cy + fmaxf(pb.w, 0.0f) * st;
            float iw = fmaxf(fminf(x2, gx2) - fmaxf(x1, gx1), 0.0f);
            float ih = fmaxf(fminf(y2, gy2) - fmaxf(y1, gy1), 0.0f);
            float inter = iw * ih;
            float t = fmaxf(inter / ((x2 - x1) * (y2 - y1) + garea - inter), 1e-9f);
            float l = pred_scores[(size_t)(b * A_TOT + a) * NCLS + lb];
            corr = focal_t(l, t) - focal0(l);
            boxl = ciou_(x1, y1, x2, y2, gx1, gy1, gx2, gy2);
        }
        s_corr[tid] = corr;
        s_boxl[tid] = boxl;
        s_keep[tid] = keep;
    }
    __syncthreads();
    if (tid == 0) {
        float cs = 0.0f, bs = 0.0f;
        int np = 0;
        for (int k = 0; k < TOPK; k++) { cs += s_corr[k]; bs += s_boxl[k]; np += s_keep[k]; }
        ws_corr[b] = cs;
        ws_box[b]  = bs;
        ws_np[b]   = np;
    }

    // ---- assign block joins focal: one strided unit (half share), NT loads ----
    {
        const int base = (2 * NB_F + b) * BLK + tid;
        for (int i = base; i < n4; i += N_UNIT * BLK) {
            vfloat4 v = ldnt4(p4 + i);
            acc += focal4v(v);
        }
        for (int o = 32; o > 0; o >>= 1) acc += __shfl_down(acc, o, 64);
        if ((tid & 63) == 0) s_rv[tid >> 6] = acc;   // safe: all prior s_rv reads are barrier-separated
        __syncthreads();
        if (tid < 16) {
            float v2 = s_rv[tid];
            for (int o = 8; o > 0; o >>= 1) v2 += __shfl_down(v2, o, 64);
            if (tid == 0) ws_focal[blockIdx.x] = v2;
        }
    }
}

// ---------- finalize: one wave reduces all partials ----------

__global__ __launch_bounds__(64) void finalize_kernel(const float* __restrict__ ws_focal,
                                                      const float* __restrict__ ws_corr,
                                                      const float* __restrict__ ws_box,
                                                      const int* __restrict__ ws_np,
                                                      float* __restrict__ out, int B) {
    int tid = threadIdx.x;
    float c = 0.0f, bx = 0.0f;
    int np = 0;
    for (int i = tid; i < NB_TOT; i += 64) c += ws_focal[i];
    for (int i = tid; i < B; i += 64) { c += ws_corr[i]; bx += ws_box[i]; np += ws_np[i]; }
    for (int o = 32; o > 0; o >>= 1) {
        c  += __shfl_down(c, o, 64);
        bx += __shfl_down(bx, o, 64);
        np += __shfl_down(np, o, 64);
    }
    if (tid == 0) {
        float npos = fmaxf((float)np, 1.0f);
        out[0] = c / npos + 2.5f * bx / npos;
    }
}

// ---------- launch ----------

extern "C" void kernel_launch(void* const* d_in, const int* in_sizes, int n_in,
                              void* d_out, int out_size, void* d_ws, size_t ws_size,
                              hipStream_t stream) {
    const float* pred_boxes  = (const float*)d_in[0];
    const float* pred_scores = (const float*)d_in[1];
    const float* gt_bboxes   = (const float*)d_in[2];
    const int*   gt_labels   = (const int*)d_in[3];
    float* out = (float*)d_out;

    const int B  = in_sizes[3];          // 64 images
    const int n4 = in_sizes[1] / 4;      // float4 count of pred_scores

    float* ws_focal = (float*)d_ws;          // [NB_TOT]
    float* ws_corr  = ws_focal + NB_TOT;     // [B]
    float* ws_box   = ws_corr + B;           // [B]
    int*   ws_np    = (int*)(ws_box + B);    // [B]

    fused_kernel<<<NB_TOT, BLK, 0, stream>>>(pred_boxes, pred_scores, gt_bboxes, gt_labels,
                                             ws_focal, ws_corr, ws_box, ws_np, n4);
    finalize_kernel<<<1, 64, 0, stream>>>(ws_focal, ws_corr, ws_box, ws_np, out, B);
}